// Round 2
// baseline (94.323 us; speedup 1.0000x reference)
//
#include <hip/hip_runtime.h>
#include <stdint.h>

#define N_PEDS 4096
typedef unsigned long long u64;
typedef unsigned int u32;

__device__ __forceinline__ u64 u64min(u64 a, u64 b) { return a < b ? a : b; }
__device__ __forceinline__ u64 u64max(u64 a, u64 b) { return a < b ? b : a; }
__device__ __forceinline__ u32 u32min(u32 a, u32 b) { return a < b ? a : b; }
__device__ __forceinline__ u32 u32max(u32 a, u32 b) { return a < b ? b : a; }
__device__ __forceinline__ void ce32(u32& a, u32& b) {
    u32 lo = u32min(a, b); b = u32max(a, b); a = lo;
}

// One wave per pedestrian i. Block = 512 threads = 8 waves = 8 i's.
// Grid = 512 blocks -> 2 blocks/CU, 16 waves/CU.
//
// R2 = DIAGNOSTIC ROUND: kernel body identical to R1 (verified passing).
// kernel_launch enqueues the kernel 4x back-to-back (idempotent: pure
// function of inputs, every output element written exactly once, so the
// replay is bit-identical). dur_us becomes fill + 4X + overhead instead of
// fill + X + overhead -> solves for the kernel's own device time X, which
// rocprof's top-5 (all 39us harness poison fills) cannot show.
__global__ __launch_bounds__(512, 4) void nn_tag_pool_kernel(
    const float* __restrict__ obs1, const float* __restrict__ obs2,
    const float* __restrict__ W, const float* __restrict__ b,
    float* __restrict__ out)
{
    __shared__ __align__(16) float2 pos[N_PEDS];
    __shared__ float sW[48];
    __shared__ float sB[8];

    const int tid = threadIdx.x;

    // Stage obs2 -> LDS: 2048 float4, 4 per thread, coalesced.
    {
        const float4* src = (const float4*)obs2;
        float4* dst = (float4*)pos;
        #pragma unroll
        for (int k = 0; k < 4; ++k) dst[tid + k * 512] = src[tid + k * 512];
    }
    if (tid < 48) sW[tid] = W[tid];
    if (tid < 8)  sB[tid] = b[tid];
    __syncthreads();

    const int wave = tid >> 6;
    const int lane = tid & 63;
    const int i = blockIdx.x * 8 + wave;

    const float2 pi = pos[i];
    const float xi = pi.x, yi = pi.y;

    // Hoist the uniform epilogue load: hides its global latency under the scan.
    const float2 o1i = ((const float2*)obs1)[i];

    u32 t0 = 0xFFFFFFFFu, t1 = 0xFFFFFFFFu, t2 = 0xFFFFFFFFu, t3 = 0xFFFFFFFFu;

    const float4* pos4 = (const float4*)pos;

    // 16 iters x 4 candidates, software-pipelined one iteration ahead.
    float4 pa = pos4[lane];
    float4 pb = pos4[lane + 64];

    #pragma unroll
    for (int it = 0; it < 16; ++it) {
        const float4 ca = pa;
        const float4 cb = pb;
        if (it != 15) {  // compile-time folded under full unroll
            const int jn = lane + ((it + 1) << 7);
            pa = pos4[jn];
            pb = pos4[jn + 64];
        }
        const u32 bl = (u32)(it << 2);

        // Reference op order, no fma contraction:
        float ax = __fsub_rn(ca.x, xi), ay = __fsub_rn(ca.y, yi);
        float da0 = __fadd_rn(__fadd_rn(__fmul_rn(ax, ax), __fmul_rn(ay, ay)), 1.0f);
        float az = __fsub_rn(ca.z, xi), aw = __fsub_rn(ca.w, yi);
        float da1 = __fadd_rn(__fadd_rn(__fmul_rn(az, az), __fmul_rn(aw, aw)), 1.0f);
        float bx = __fsub_rn(cb.x, xi), by = __fsub_rn(cb.y, yi);
        float db0 = __fadd_rn(__fadd_rn(__fmul_rn(bx, bx), __fmul_rn(by, by)), 1.0f);
        float bz = __fsub_rn(cb.z, xi), bw = __fsub_rn(cb.w, yi);
        float db1 = __fadd_rn(__fadd_rn(__fmul_rn(bz, bz), __fmul_rn(bw, bw)), 1.0f);

        u32 c0 = ((__float_as_uint(da0) - 0x3F800000u) << 6) | (bl + 0u);
        u32 c1 = ((__float_as_uint(da1) - 0x3F800000u) << 6) | (bl + 1u);
        u32 c2 = ((__float_as_uint(db0) - 0x3F800000u) << 6) | (bl + 2u);
        u32 c3 = ((__float_as_uint(db1) - 0x3F800000u) << 6) | (bl + 3u);

        // full sort-4 of candidates (5 comparators)
        ce32(c0, c1); ce32(c2, c3); ce32(c0, c2); ce32(c1, c3); ce32(c1, c2);
        // t(asc) ++ c(desc) bitonic lower-half, then bitonic sort-4
        u32 e0 = u32min(t0, c3);
        u32 e1 = u32min(t1, c2);
        u32 e2 = u32min(t2, c1);
        u32 e3 = u32min(t3, c0);
        ce32(e0, e2); ce32(e1, e3); ce32(e0, e1); ce32(e2, e3);
        t0 = e0; t1 = e1; t2 = e2; t3 = e3;
    }

    // Remove self (key == local_self exactly, rel==0) in the owning lane.
    {
        const int j2s = i >> 1;
        const u32 ks = (u32)(((j2s >> 7) << 2) | (((j2s >> 6) & 1) << 1) | (i & 1));
        const bool sl = (lane == (j2s & 63));
        bool e0 = sl && (t0 == ks);
        bool e1 = sl && (t1 == ks);
        bool e2 = sl && (t2 == ks);
        bool e3 = sl && (t3 == ks);
        bool a1 = e0 | e1, a2 = a1 | e2, a3 = a2 | e3;
        t0 = e0 ? t1 : t0;
        t1 = a1 ? t2 : t1;
        t2 = a2 ? t3 : t2;
        t3 = a3 ? 0xFFFFFFFFu : t3;
    }

    // Rebuild exact u64 keys (rel<<18 | global_j) for the cross-lane merge.
    // j = 2*lane + (local>>2)*256 + ((local>>1)&1)*128 + (local&1)
    u64 k0, k1, k2, k3;
    {
        u32 s[4] = { t0, t1, t2, t3 };
        u64 kk[4];
        #pragma unroll
        for (int q = 0; q < 4; ++q) {
            u32 local = s[q] & 63u;
            u32 j = (u32)(lane << 1) + ((local >> 2) << 8)
                  + (((local >> 1) & 1u) << 7) + (local & 1u);
            kk[q] = ((u64)(s[q] & 0xFFFFFFC0u) << 12) | j;
        }
        k0 = kk[0]; k1 = kk[1]; k2 = kk[2]; k3 = kk[3];
    }

    // Butterfly merge across 64 lanes: 6 steps, exact u64 keys.
    #pragma unroll
    for (int m = 1; m < 64; m <<= 1) {
        u64 b0 = __shfl_xor(k0, m, 64);
        u64 b1 = __shfl_xor(k1, m, 64);
        u64 b2 = __shfl_xor(k2, m, 64);
        u64 b3 = __shfl_xor(k3, m, 64);
        u64 e0 = u64min(k0, b3);
        u64 e1 = u64min(k1, b2);
        u64 e2 = u64min(k2, b1);
        u64 e3 = u64min(k3, b0);
        u64 f0 = u64min(e0, e2), f2 = u64max(e0, e2);
        u64 f1 = u64min(e1, e3), f3 = u64max(e1, e3);
        k0 = u64min(f0, f1); k1 = u64max(f0, f1);
        k2 = u64min(f2, f3); k3 = u64max(f2, f3);
    }

    // Epilogue: lanes 0..31 each produce one output element.
    if (lane < 32) {
        const int k = lane >> 3;   // neighbor rank
        const int o = lane & 7;    // embedding channel
        u64 tk = (k == 0) ? k0 : (k == 1) ? k1 : (k == 2) ? k2 : k3;
        const int j = (int)(tk & 0xFFFu);

        float2 pj = pos[j];
        float2 o1j = ((const float2*)obs1)[j];
        float px = pj.x - xi;
        float py = pj.y - yi;
        float vx = (pj.x - o1j.x) - (xi - o1i.x);
        float vy = (pj.y - o1j.y) - (yi - o1i.y);

        const float* w = &sW[o * 6];
        float acc = sB[o] + w[0] * px + w[1] * py + w[2]
                          + w[3] * vx + w[4] * vy + w[5];
        out[i * 32 + k * 8 + o] = acc > 0.0f ? acc : 0.0f;
    }
}

extern "C" void kernel_launch(void* const* d_in, const int* in_sizes, int n_in,
                              void* d_out, int out_size, void* d_ws, size_t ws_size,
                              hipStream_t stream) {
    const float* obs1 = (const float*)d_in[0];
    const float* obs2 = (const float*)d_in[1];
    const float* W    = (const float*)d_in[2];
    const float* b    = (const float*)d_in[3];
    float* out        = (float*)d_out;

    // DIAGNOSTIC: 4 identical launches. Output is bit-identical (kernel is a
    // pure function of inputs; every output element written exactly once).
    // dur_us = fill + 4X + overhead  =>  X = (dur4 - dur1)/3.
    for (int r = 0; r < 4; ++r) {
        hipLaunchKernelGGL(nn_tag_pool_kernel, dim3(N_PEDS / 8), dim3(512), 0, stream,
                           obs1, obs2, W, b, out);
    }
}

// Round 3
// 67.157 us; speedup vs baseline: 1.4045x; 1.4045x over previous
//
#include <hip/hip_runtime.h>
#include <stdint.h>

#define N_PEDS 4096
typedef unsigned long long u64;
typedef unsigned int u32;
typedef float v2f __attribute__((ext_vector_type(2)));
typedef float v4f __attribute__((ext_vector_type(4)));

__device__ __forceinline__ u64 u64min(u64 a, u64 b) { return a < b ? a : b; }
__device__ __forceinline__ u64 u64max(u64 a, u64 b) { return a < b ? b : a; }
__device__ __forceinline__ u32 u32min(u32 a, u32 b) { return a < b ? a : b; }
__device__ __forceinline__ u32 u32max(u32 a, u32 b) { return a < b ? b : a; }
__device__ __forceinline__ void ce32(u32& a, u32& b) {
    u32 lo = u32min(a, b); b = u32max(a, b); a = lo;
}

// IEEE-exact packed helpers. a + (-b) == a - b bit-exactly (IEEE 754, rn);
// v_pk_* round each half with rn => identical to __fsub_rn/__fmul_rn pairs.
__device__ __forceinline__ v2f pk_sub(v2f a, v2f b) {
    v2f d;
    asm("v_pk_add_f32 %0, %1, %2 neg_lo:[0,1] neg_hi:[0,1]"
        : "=v"(d) : "v"(a), "v"(b));
    return d;
}
__device__ __forceinline__ v2f pk_sqr(v2f a) {
    v2f d;
    asm("v_pk_mul_f32 %0, %1, %1" : "=v"(d) : "v"(a));
    return d;
}

// One wave per pedestrian i. Block = 512 threads = 8 waves = 8 i's.
// Grid = 512 blocks -> 2 blocks/CU, 16 waves/CU (one residency generation).
//
// Scan: EXACT 32-bit keys key = ((dist_bits - bits(1.0)) << 6) | local_id,
// computed as (dist_bits << 6) + (0x20000000 + local_id):
//   (b - 0x3F800000) << 6 == (b << 6) - 0xE0000000 (mod 2^32)
//   => key == (b << 6) + (local_id + 0x20000000) (mod 2^32), one v_lshl_add.
//   Valid because rel = b - 0x3F800000 < 2^26 (d < 256; gaussian d <= ~163).
// Self-exclusion: self has dx=dy=0 exactly => rel=0 => key == local_self
//   (unique per lane); removed post-scan by predicated shift-down.
// Merge: rebuild u64 (rel, global_j) keys => cross-lane tie-break exact.
//
// R3: packed-f32 distance math (v_pk asm, 4->2 ops/candidate) + 1-op key
// packing. Key VALUES identical to baseline => all downstream logic
// (self-removal, rebuild, butterfly) unchanged. Single launch restored.
__global__ __launch_bounds__(512, 4) void nn_tag_pool_kernel(
    const float* __restrict__ obs1, const float* __restrict__ obs2,
    const float* __restrict__ W, const float* __restrict__ b,
    float* __restrict__ out)
{
    __shared__ __align__(16) float2 pos[N_PEDS];
    __shared__ float sW[48];
    __shared__ float sB[8];

    const int tid = threadIdx.x;

    // Stage obs2 -> LDS: 2048 float4, 4 per thread, coalesced.
    {
        const float4* src = (const float4*)obs2;
        float4* dst = (float4*)pos;
        #pragma unroll
        for (int k = 0; k < 4; ++k) dst[tid + k * 512] = src[tid + k * 512];
    }
    if (tid < 48) sW[tid] = W[tid];
    if (tid < 8)  sB[tid] = b[tid];
    __syncthreads();

    const int wave = tid >> 6;
    const int lane = tid & 63;
    const int i = blockIdx.x * 8 + wave;

    const float2 pi = pos[i];
    const float xi = pi.x, yi = pi.y;
    v2f pc; pc.x = xi; pc.y = yi;

    // Hoist the uniform epilogue load: hides its global latency under the scan.
    const float2 o1i = ((const float2*)obs1)[i];

    u32 t0 = 0xFFFFFFFFu, t1 = 0xFFFFFFFFu, t2 = 0xFFFFFFFFu, t3 = 0xFFFFFFFFu;

    const v4f* pos4 = (const v4f*)pos;

    // 16 iters x 4 candidates, software-pipelined one iteration ahead.
    v4f pa = pos4[lane];
    v4f pb = pos4[lane + 64];

    #pragma unroll
    for (int it = 0; it < 16; ++it) {
        const v4f ca = pa;
        const v4f cb = pb;
        if (it != 15) {  // compile-time folded under full unroll
            const int jn = lane + ((it + 1) << 7);
            pa = pos4[jn];
            pb = pos4[jn + 64];
        }
        const u32 K = 0x20000000u + (u32)(it << 2);

        // Packed diff + square, scalar horizontal sum (ref op order, rn each):
        v2f qa0 = pk_sqr(pk_sub(ca.xy, pc));
        v2f qa1 = pk_sqr(pk_sub(ca.zw, pc));
        v2f qb0 = pk_sqr(pk_sub(cb.xy, pc));
        v2f qb1 = pk_sqr(pk_sub(cb.zw, pc));
        float da0 = __fadd_rn(__fadd_rn(qa0.x, qa0.y), 1.0f);
        float da1 = __fadd_rn(__fadd_rn(qa1.x, qa1.y), 1.0f);
        float db0 = __fadd_rn(__fadd_rn(qb0.x, qb0.y), 1.0f);
        float db1 = __fadd_rn(__fadd_rn(qb1.x, qb1.y), 1.0f);

        u32 c0 = (__float_as_uint(da0) << 6) + (K + 0u);
        u32 c1 = (__float_as_uint(da1) << 6) + (K + 1u);
        u32 c2 = (__float_as_uint(db0) << 6) + (K + 2u);
        u32 c3 = (__float_as_uint(db1) << 6) + (K + 3u);

        // full sort-4 of candidates (5 comparators)
        ce32(c0, c1); ce32(c2, c3); ce32(c0, c2); ce32(c1, c3); ce32(c1, c2);
        // t(asc) ++ c(desc) bitonic lower-half, then bitonic sort-4
        u32 e0 = u32min(t0, c3);
        u32 e1 = u32min(t1, c2);
        u32 e2 = u32min(t2, c1);
        u32 e3 = u32min(t3, c0);
        ce32(e0, e2); ce32(e1, e3); ce32(e0, e1); ce32(e2, e3);
        t0 = e0; t1 = e1; t2 = e2; t3 = e3;
    }

    // Remove self (key == local_self exactly, rel==0) in the owning lane.
    {
        const int j2s = i >> 1;
        const u32 ks = (u32)(((j2s >> 7) << 2) | (((j2s >> 6) & 1) << 1) | (i & 1));
        const bool sl = (lane == (j2s & 63));
        bool e0 = sl && (t0 == ks);
        bool e1 = sl && (t1 == ks);
        bool e2 = sl && (t2 == ks);
        bool e3 = sl && (t3 == ks);
        bool a1 = e0 | e1, a2 = a1 | e2, a3 = a2 | e3;
        t0 = e0 ? t1 : t0;
        t1 = a1 ? t2 : t1;
        t2 = a2 ? t3 : t2;
        t3 = a3 ? 0xFFFFFFFFu : t3;
    }

    // Rebuild exact u64 keys (rel<<18 | global_j) for the cross-lane merge.
    // j = 2*lane + (local>>2)*256 + ((local>>1)&1)*128 + (local&1)
    u64 k0, k1, k2, k3;
    {
        u32 s[4] = { t0, t1, t2, t3 };
        u64 kk[4];
        #pragma unroll
        for (int q = 0; q < 4; ++q) {
            u32 local = s[q] & 63u;
            u32 j = (u32)(lane << 1) + ((local >> 2) << 8)
                  + (((local >> 1) & 1u) << 7) + (local & 1u);
            kk[q] = ((u64)(s[q] & 0xFFFFFFC0u) << 12) | j;
        }
        k0 = kk[0]; k1 = kk[1]; k2 = kk[2]; k3 = kk[3];
    }

    // Butterfly merge across 64 lanes: 6 steps, exact u64 keys.
    #pragma unroll
    for (int m = 1; m < 64; m <<= 1) {
        u64 b0 = __shfl_xor(k0, m, 64);
        u64 b1 = __shfl_xor(k1, m, 64);
        u64 b2 = __shfl_xor(k2, m, 64);
        u64 b3 = __shfl_xor(k3, m, 64);
        u64 e0 = u64min(k0, b3);
        u64 e1 = u64min(k1, b2);
        u64 e2 = u64min(k2, b1);
        u64 e3 = u64min(k3, b0);
        u64 f0 = u64min(e0, e2), f2 = u64max(e0, e2);
        u64 f1 = u64min(e1, e3), f3 = u64max(e1, e3);
        k0 = u64min(f0, f1); k1 = u64max(f0, f1);
        k2 = u64min(f2, f3); k3 = u64max(f2, f3);
    }

    // Epilogue: lanes 0..31 each produce one output element.
    if (lane < 32) {
        const int k = lane >> 3;   // neighbor rank
        const int o = lane & 7;    // embedding channel
        u64 tk = (k == 0) ? k0 : (k == 1) ? k1 : (k == 2) ? k2 : k3;
        const int j = (int)(tk & 0xFFFu);

        float2 pj = pos[j];
        float2 o1j = ((const float2*)obs1)[j];
        float px = pj.x - xi;
        float py = pj.y - yi;
        float vx = (pj.x - o1j.x) - (xi - o1i.x);
        float vy = (pj.y - o1j.y) - (yi - o1i.y);

        const float* w = &sW[o * 6];
        float acc = sB[o] + w[0] * px + w[1] * py + w[2]
                          + w[3] * vx + w[4] * vy + w[5];
        out[i * 32 + k * 8 + o] = acc > 0.0f ? acc : 0.0f;
    }
}

extern "C" void kernel_launch(void* const* d_in, const int* in_sizes, int n_in,
                              void* d_out, int out_size, void* d_ws, size_t ws_size,
                              hipStream_t stream) {
    const float* obs1 = (const float*)d_in[0];
    const float* obs2 = (const float*)d_in[1];
    const float* W    = (const float*)d_in[2];
    const float* b    = (const float*)d_in[3];
    float* out        = (float*)d_out;

    hipLaunchKernelGGL(nn_tag_pool_kernel, dim3(N_PEDS / 8), dim3(512), 0, stream,
                       obs1, obs2, W, b, out);
}